// Round 3
// baseline (872.937 us; speedup 1.0000x reference)
//
#include <hip/hip_runtime.h>

#define E_N   8
#define IN_N  4096
#define OUT_N 4096
#define T_N   8192

#define BM 128
#define BN 256
#define BK 64
#define LDK (BK + 8)          // +8 u16 pad -> row stride 144B, conflict-light
#define NTHREADS 512

typedef unsigned short u16;
typedef __bf16 bf16_t;
typedef bf16_t bf16x8 __attribute__((ext_vector_type(8)));
typedef u16    u16x8  __attribute__((ext_vector_type(8)));
typedef float  f32x4  __attribute__((ext_vector_type(4)));

// ---- device-global scratch (d_ws size is unknown -> don't trust it) ----
__device__ int g_cnt[E_N];
__device__ int g_base[E_N];
__device__ int g_ids[T_N];
__device__ int g_meta_wide;    // 1 if meta was widened int16->int32 on device

__device__ __forceinline__ u16 f2bf(float f) {
    unsigned u = __builtin_bit_cast(unsigned, f);
    u += 0x7FFFu + ((u >> 16) & 1u);     // round-to-nearest-even
    return (u16)(u >> 16);
}

// ---------------- kernel 1: bucket tokens by expert + meta-layout probe ----------------
__global__ void sort_tokens(const int* __restrict__ idx, const u16* __restrict__ meta16) {
    __shared__ int cnt[E_N], off[E_N];
    __shared__ int probe;
    const int tid = threadIdx.x;
    if (tid == 0) probe = 0;
    if (tid < E_N) cnt[tid] = 0;
    __syncthreads();
    // probe: if meta is int32-widened, u16 halves at odd indices (2i+1) are all 0
    if (tid < 64) {
        unsigned v = meta16[2 * (tid * 131072) + 1];   // max index 16.5M u16 -> safe for either layout
        if (v) atomicOr(&probe, 1);
    }
    for (int t = tid; t < T_N; t += blockDim.x) atomicAdd(&cnt[idx[t] & 7], 1);
    __syncthreads();
    if (tid == 0) {
        int s = 0;
        for (int e = 0; e < E_N; ++e) { g_cnt[e] = cnt[e]; g_base[e] = s; off[e] = s; s += cnt[e]; }
        g_meta_wide = (probe == 0) ? 1 : 0;
    }
    __syncthreads();
    for (int t = tid; t < T_N; t += blockDim.x) {
        int p = atomicAdd(&off[idx[t] & 7], 1);
        if (p >= 0 && p < T_N) g_ids[p] = t;
    }
}

// ---------------- kernel 2: fused decode + grouped GEMM ----------------
__global__ __launch_bounds__(NTHREADS, 1)
void moe_sp_gemm(const float* __restrict__ x,        // f32 (T, IN)  [fp16 upcast by harness]
                 const int* __restrict__ qw,         // (E, IN/32, OUT*2) int32
                 const void* __restrict__ meta,      // (E, OUT, IN/16) int16 or widened int32
                 const float* __restrict__ scales,   // f32 (E, OUT)
                 float* __restrict__ y)              // f32 (T, OUT)
{
    const int e = blockIdx.z;
    int cnt = g_cnt[e];
    if (cnt < 0) cnt = 0;
    if (cnt > T_N) cnt = T_N;
    const int m0 = blockIdx.y * BM;
    if (m0 >= cnt) return;
    const int n0 = blockIdx.x * BN;
    int base = g_base[e];
    if (base < 0) base = 0;
    if (base > T_N - cnt) base = T_N - cnt;
    const int* toks = g_ids + base;
    const bool mwide = (g_meta_wide != 0);

    __shared__ __align__(16) u16 As[BM][LDK];
    __shared__ __align__(16) u16 Bs[BN][LDK];

    const int tid  = threadIdx.x;
    const int lane = tid & 63;
    const int wid  = tid >> 6;
    const int wm   = wid >> 2;     // 0..1
    const int wn   = wid & 3;      // 0..3

    // A staging: 4 threads per row, 16 f32 each
    const int ar = tid >> 2;       // 0..127
    const int aq = tid & 3;        // 0..3
    int atok = -1;
    if (m0 + ar < cnt) {
        atok = toks[m0 + ar];
        if ((unsigned)atok >= (unsigned)T_N) atok = 0;
    }
    const float* axp = x + (long)(atok < 0 ? 0 : atok) * IN_N;

    f32x4 acc[4][4];
    #pragma unroll
    for (int i = 0; i < 4; ++i)
        #pragma unroll
        for (int j = 0; j < 4; ++j) acc[i][j] = (f32x4){0.f, 0.f, 0.f, 0.f};

    for (int k0 = 0; k0 < IN_N; k0 += BK) {
        // ---- stage A: load 16 f32, convert to bf16, write 2x16B ----
        {
            float va[16];
            #pragma unroll
            for (int c4 = 0; c4 < 4; ++c4) {
                float4 v = make_float4(0.f, 0.f, 0.f, 0.f);
                if (atok >= 0) v = *reinterpret_cast<const float4*>(axp + k0 + aq * 16 + c4 * 4);
                va[c4 * 4 + 0] = v.x; va[c4 * 4 + 1] = v.y; va[c4 * 4 + 2] = v.z; va[c4 * 4 + 3] = v.w;
            }
            unsigned wp[8];
            #pragma unroll
            for (int p = 0; p < 8; ++p)
                wp[p] = (unsigned)f2bf(va[2 * p]) | ((unsigned)f2bf(va[2 * p + 1]) << 16);
            *reinterpret_cast<int4*>(&As[ar][aq * 16])     = make_int4((int)wp[0], (int)wp[1], (int)wp[2], (int)wp[3]);
            *reinterpret_cast<int4*>(&As[ar][aq * 16 + 8]) = make_int4((int)wp[4], (int)wp[5], (int)wp[6], (int)wp[7]);
        }
        // ---- decode B tile: 256 cols x 4 sixteen-blocks = 1024 items, 2/thread ----
        #pragma unroll
        for (int it = 0; it < 2; ++it) {
            const int idx2 = tid + it * NTHREADS;
            const int c  = idx2 & (BN - 1);
            const int gi = idx2 >> 8;                // 0..3
            const int o  = n0 + c;
            const int g  = (k0 >> 4) + gi;           // 16-block index (0..255)
            const int midx = (e * OUT_N + o) * (IN_N / 16) + g;
            unsigned mw;
            if (mwide) mw = (unsigned)((const int*)meta)[midx] & 0xFFFFu;
            else       mw = (unsigned)((const u16*)meta)[midx];
            const unsigned sh = (o & 7) << 2;
            const int* qp = qw + ((e * (IN_N / 32) + (g >> 1)) << 13) + (o >> 3) + ((g & 1) << 12);
            int d[16];
            #pragma unroll
            for (int p = 0; p < 16; ++p) d[p] = 0;
            #pragma unroll
            for (int grp = 0; grp < 4; ++grp) {
                const unsigned w0 = (unsigned)qp[(2 * grp) * 512];
                const unsigned w1 = (unsigned)qp[(2 * grp + 1) * 512];
                const int v0 = (int)((w0 >> sh) & 0xF) - 8;
                const int v1 = (int)((w1 >> sh) & 0xF) - 8;
                const int s0 = (mw >> (4 * grp)) & 3;
                const int s1 = (mw >> (4 * grp + 2)) & 3;
                #pragma unroll
                for (int q = 0; q < 4; ++q) {
                    int t0 = (s0 == q) ? v0 : 0;
                    int t1 = (s1 == q) ? v1 : 0;
                    d[grp * 4 + q] = t0 + t1;        // collisions sum, matching .at[].add
                }
            }
            unsigned wp[8];
            #pragma unroll
            for (int p = 0; p < 8; ++p) {
                unsigned lo = __builtin_bit_cast(unsigned, (float)d[2 * p])     >> 16;  // exact for |d|<=30
                unsigned hi = __builtin_bit_cast(unsigned, (float)d[2 * p + 1]) >> 16;
                wp[p] = lo | (hi << 16);
            }
            *reinterpret_cast<int4*>(&Bs[c][gi * 16])     = make_int4((int)wp[0], (int)wp[1], (int)wp[2], (int)wp[3]);
            *reinterpret_cast<int4*>(&Bs[c][gi * 16 + 8]) = make_int4((int)wp[4], (int)wp[5], (int)wp[6], (int)wp[7]);
        }
        __syncthreads();
        // ---- MFMA ----
        #pragma unroll
        for (int kk = 0; kk < BK; kk += 32) {
            bf16x8 af[4], bfr[4];
            #pragma unroll
            for (int mf = 0; mf < 4; ++mf) {
                u16x8 r = *reinterpret_cast<const u16x8*>(&As[wm * 64 + mf * 16 + (lane & 15)][kk + ((lane >> 4) << 3)]);
                af[mf] = __builtin_bit_cast(bf16x8, r);
            }
            #pragma unroll
            for (int nf = 0; nf < 4; ++nf) {
                u16x8 r = *reinterpret_cast<const u16x8*>(&Bs[wn * 64 + nf * 16 + (lane & 15)][kk + ((lane >> 4) << 3)]);
                bfr[nf] = __builtin_bit_cast(bf16x8, r);
            }
            #pragma unroll
            for (int mf = 0; mf < 4; ++mf)
                #pragma unroll
                for (int nf = 0; nf < 4; ++nf)
                    acc[mf][nf] = __builtin_amdgcn_mfma_f32_16x16x32_bf16(af[mf], bfr[nf], acc[mf][nf], 0, 0, 0);
        }
        __syncthreads();
    }

    // ---- epilogue: scale per (e, col), f32 store, scatter rows by token id ----
    float sc[4];
    #pragma unroll
    for (int nf = 0; nf < 4; ++nf)
        sc[nf] = scales[e * OUT_N + n0 + wn * 64 + nf * 16 + (lane & 15)];
    #pragma unroll
    for (int mf = 0; mf < 4; ++mf) {
        #pragma unroll
        for (int r = 0; r < 4; ++r) {
            const int row = m0 + wm * 64 + mf * 16 + ((lane >> 4) << 2) + r;
            if (row >= cnt) continue;
            int tok = toks[row];
            if ((unsigned)tok >= (unsigned)T_N) continue;
            float* yrow = y + (long)tok * OUT_N;
            #pragma unroll
            for (int nf = 0; nf < 4; ++nf) {
                const int col = n0 + wn * 64 + nf * 16 + (lane & 15);
                yrow[col] = acc[mf][nf][r] * sc[nf];
            }
        }
    }
}

extern "C" void kernel_launch(void* const* d_in, const int* in_sizes, int n_in,
                              void* d_out, int out_size, void* d_ws, size_t ws_size,
                              hipStream_t stream) {
    // Route inputs by element-count signature (order-robust):
    //   x: 33554432, indices: 8192, scales: 32768, qweight & meta: 8388608 each (dict order: qw first)
    const float* x      = nullptr;
    const int* indices  = nullptr;
    const int* qw       = nullptr;
    const void* meta    = nullptr;
    const float* scales = nullptr;
    int big_seen = 0;
    for (int i = 0; i < n_in; ++i) {
        long s = in_sizes[i];
        if (s == 33554432L)      x = (const float*)d_in[i];
        else if (s == 8192L)     indices = (const int*)d_in[i];
        else if (s == 32768L)    scales = (const float*)d_in[i];
        else if (s == 8388608L) {
            if (big_seen++ == 0)  qw = (const int*)d_in[i];
            else                  meta = d_in[i];
        }
    }
    if (!x || !indices || !qw || !meta || !scales) return;  // leaves out=0 -> bounded diagnostic
    float* y = (float*)d_out;

    hipLaunchKernelGGL(sort_tokens, dim3(1), dim3(1024), 0, stream,
                       indices, (const u16*)meta);
    dim3 grid(OUT_N / BN, T_N / BM, E_N);
    hipLaunchKernelGGL(moe_sp_gemm, grid, dim3(NTHREADS), 0, stream,
                       x, qw, meta, scales, y);
}

// Round 4
// 630.599 us; speedup vs baseline: 1.3843x; 1.3843x over previous
//
#include <hip/hip_runtime.h>

#define E_N   8
#define IN_N  4096
#define OUT_N 4096
#define T_N   8192

#define BM 128
#define BN 256
#define BK 64
#define LDK (BK + 8)          // +8 u16 pad -> row stride 144B, conflict-light
#define NTHREADS 512

typedef unsigned short u16;
typedef __bf16 bf16_t;
typedef bf16_t bf16x8 __attribute__((ext_vector_type(8)));
typedef u16    u16x8  __attribute__((ext_vector_type(8)));
typedef float  f32x4  __attribute__((ext_vector_type(4)));

// ---- device-global scratch (ws_size unknown -> use module globals) ----
__device__ int g_cnt[E_N];
__device__ int g_base[E_N];
__device__ int g_ids[T_N];
__device__ int g_meta_wide;                       // 1 if meta widened int16->int32
__device__ u16 g_W[(long)E_N * OUT_N * IN_N];     // 268 MB dense bf16 weights, k-contiguous
__device__ u16 g_xb[(long)T_N * IN_N];            // 67 MB sorted bf16 tokens

__device__ __forceinline__ u16 f2bf(float f) {
    unsigned u = __builtin_bit_cast(unsigned, f);
    u += 0x7FFFu + ((u >> 16) & 1u);              // round-to-nearest-even
    return (u16)(u >> 16);
}

// ---------------- kernel 1: bucket tokens by expert + meta-layout probe ----------------
__global__ void sort_tokens(const int* __restrict__ idx, const u16* __restrict__ meta16) {
    __shared__ int cnt[E_N], off[E_N];
    __shared__ int probe;
    const int tid = threadIdx.x;
    if (tid == 0) probe = 0;
    if (tid < E_N) cnt[tid] = 0;
    __syncthreads();
    // if meta is int32-widened, u16 halves at odd indices are all 0
    if (tid < 64) {
        unsigned v = meta16[2 * (tid * 131072) + 1];   // safe for either layout
        if (v) atomicOr(&probe, 1);
    }
    for (int t = tid; t < T_N; t += blockDim.x) atomicAdd(&cnt[idx[t] & 7], 1);
    __syncthreads();
    if (tid == 0) {
        int s = 0;
        for (int e = 0; e < E_N; ++e) { g_cnt[e] = cnt[e]; g_base[e] = s; off[e] = s; s += cnt[e]; }
        g_meta_wide = (probe == 0) ? 1 : 0;
    }
    __syncthreads();
    for (int t = tid; t < T_N; t += blockDim.x) {
        int p = atomicAdd(&off[idx[t] & 7], 1);
        if (p >= 0 && p < T_N) g_ids[p] = t;
    }
}

// ---------------- kernel 2: gather + convert x (f32) -> sorted bf16 rows ----------------
__global__ __launch_bounds__(256, 4)
void xb_convert(const float* __restrict__ x) {
    const int p = blockIdx.x;                     // sorted row position
    int tok = g_ids[p];
    if ((unsigned)tok >= (unsigned)T_N) tok = 0;
    const float* src = x + (long)tok * IN_N;
    u16* dst = g_xb + (long)p * IN_N;
    const int tid = threadIdx.x;                  // 16 elems per thread
    float va[16];
    #pragma unroll
    for (int c4 = 0; c4 < 4; ++c4) {
        float4 v = *reinterpret_cast<const float4*>(src + tid * 16 + c4 * 4);
        va[c4 * 4 + 0] = v.x; va[c4 * 4 + 1] = v.y; va[c4 * 4 + 2] = v.z; va[c4 * 4 + 3] = v.w;
    }
    unsigned wp[8];
    #pragma unroll
    for (int p8 = 0; p8 < 8; ++p8)
        wp[p8] = (unsigned)f2bf(va[2 * p8]) | ((unsigned)f2bf(va[2 * p8 + 1]) << 16);
    *reinterpret_cast<int4*>(dst + tid * 16)     = make_int4((int)wp[0], (int)wp[1], (int)wp[2], (int)wp[3]);
    *reinterpret_cast<int4*>(dst + tid * 16 + 8) = make_int4((int)wp[4], (int)wp[5], (int)wp[6], (int)wp[7]);
}

// ---------------- kernel 3: decode 2:4-sparse int4 -> dense bf16 W (ONCE) ----------------
__global__ __launch_bounds__(NTHREADS, 1)
void decode_w(const int* __restrict__ qw, const void* __restrict__ meta) {
    const int e  = blockIdx.z;
    const int n0 = blockIdx.x * BN;
    const int kt = blockIdx.y;                    // 64-wide k-tile index (0..63)
    const bool mwide = (g_meta_wide != 0);
    const int tid = threadIdx.x;
    #pragma unroll
    for (int it = 0; it < 2; ++it) {
        const int idx2 = tid + it * NTHREADS;
        const int c  = idx2 & (BN - 1);
        const int gi = idx2 >> 8;                 // 0..3
        const int o  = n0 + c;
        const int g  = kt * 4 + gi;               // 16-block index (0..255)
        const int midx = (e * OUT_N + o) * (IN_N / 16) + g;
        unsigned mw;
        if (mwide) mw = (unsigned)((const int*)meta)[midx] & 0xFFFFu;
        else       mw = (unsigned)((const u16*)meta)[midx];
        const unsigned sh = (o & 7) << 2;
        const int* qp = qw + ((e * (IN_N / 32) + (g >> 1)) << 13) + (o >> 3) + ((g & 1) << 12);
        int d[16];
        #pragma unroll
        for (int p = 0; p < 16; ++p) d[p] = 0;
        #pragma unroll
        for (int grp = 0; grp < 4; ++grp) {
            const unsigned w0 = (unsigned)qp[(2 * grp) * 512];
            const unsigned w1 = (unsigned)qp[(2 * grp + 1) * 512];
            const int v0 = (int)((w0 >> sh) & 0xF) - 8;
            const int v1 = (int)((w1 >> sh) & 0xF) - 8;
            const int s0 = (mw >> (4 * grp)) & 3;
            const int s1 = (mw >> (4 * grp + 2)) & 3;
            #pragma unroll
            for (int q = 0; q < 4; ++q) {
                int t0 = (s0 == q) ? v0 : 0;
                int t1 = (s1 == q) ? v1 : 0;
                d[grp * 4 + q] = t0 + t1;         // collisions sum, matching .at[].add
            }
        }
        unsigned wp[8];
        #pragma unroll
        for (int p = 0; p < 8; ++p) {
            unsigned lo = __builtin_bit_cast(unsigned, (float)d[2 * p])     >> 16;  // exact, |d|<=30
            unsigned hi = __builtin_bit_cast(unsigned, (float)d[2 * p + 1]) >> 16;
            wp[p] = lo | (hi << 16);
        }
        u16* wr = g_W + ((long)e * OUT_N + o) * IN_N + kt * 64 + gi * 16;
        *reinterpret_cast<int4*>(wr)     = make_int4((int)wp[0], (int)wp[1], (int)wp[2], (int)wp[3]);
        *reinterpret_cast<int4*>(wr + 8) = make_int4((int)wp[4], (int)wp[5], (int)wp[6], (int)wp[7]);
    }
}

// ---------------- kernel 4: grouped bf16 GEMM ----------------
__global__ __launch_bounds__(NTHREADS, 1)
void moe_gemm(const float* __restrict__ scales, float* __restrict__ y) {
    const int e = blockIdx.z;
    int cnt = g_cnt[e];
    if (cnt < 0) cnt = 0;
    if (cnt > T_N) cnt = T_N;
    const int m0 = blockIdx.y * BM;
    if (m0 >= cnt) return;
    const int n0 = blockIdx.x * BN;
    int base = g_base[e];
    if (base < 0) base = 0;
    if (base > T_N - cnt) base = T_N - cnt;

    __shared__ __align__(16) u16 As[BM][LDK];
    __shared__ __align__(16) u16 Bs[BN][LDK];

    const int tid  = threadIdx.x;
    const int lane = tid & 63;
    const int wid  = tid >> 6;
    const int wm   = wid >> 2;     // 0..1
    const int wn   = wid & 3;      // 0..3

    // A staging: 4 threads/row, 32B each (rows are sorted-contiguous in g_xb)
    const int ar = tid >> 2;
    const int aq = tid & 3;
    long arow = (long)base + m0 + ar;
    if (arow > T_N - 1) arow = T_N - 1;           // tail rows: garbage ok, never written out
    const u16* axp = g_xb + arow * IN_N;
    // B staging: 2 threads/row, 64B each
    const int br = tid >> 1;
    const int bh = tid & 1;
    const u16* bxp = g_W + ((long)e * OUT_N + n0 + br) * IN_N;

    f32x4 acc[4][4];
    #pragma unroll
    for (int i = 0; i < 4; ++i)
        #pragma unroll
        for (int j = 0; j < 4; ++j) acc[i][j] = (f32x4){0.f, 0.f, 0.f, 0.f};

    for (int k0 = 0; k0 < IN_N; k0 += BK) {
        int4 a0 = *reinterpret_cast<const int4*>(axp + k0 + aq * 16);
        int4 a1 = *reinterpret_cast<const int4*>(axp + k0 + aq * 16 + 8);
        int4 b0 = *reinterpret_cast<const int4*>(bxp + k0 + bh * 32);
        int4 b1 = *reinterpret_cast<const int4*>(bxp + k0 + bh * 32 + 8);
        int4 b2 = *reinterpret_cast<const int4*>(bxp + k0 + bh * 32 + 16);
        int4 b3 = *reinterpret_cast<const int4*>(bxp + k0 + bh * 32 + 24);
        *reinterpret_cast<int4*>(&As[ar][aq * 16])      = a0;
        *reinterpret_cast<int4*>(&As[ar][aq * 16 + 8])  = a1;
        *reinterpret_cast<int4*>(&Bs[br][bh * 32])      = b0;
        *reinterpret_cast<int4*>(&Bs[br][bh * 32 + 8])  = b1;
        *reinterpret_cast<int4*>(&Bs[br][bh * 32 + 16]) = b2;
        *reinterpret_cast<int4*>(&Bs[br][bh * 32 + 24]) = b3;
        __syncthreads();
        #pragma unroll
        for (int kk = 0; kk < BK; kk += 32) {
            bf16x8 af[4], bfr[4];
            #pragma unroll
            for (int mf = 0; mf < 4; ++mf) {
                u16x8 r = *reinterpret_cast<const u16x8*>(&As[wm * 64 + mf * 16 + (lane & 15)][kk + ((lane >> 4) << 3)]);
                af[mf] = __builtin_bit_cast(bf16x8, r);
            }
            #pragma unroll
            for (int nf = 0; nf < 4; ++nf) {
                u16x8 r = *reinterpret_cast<const u16x8*>(&Bs[wn * 64 + nf * 16 + (lane & 15)][kk + ((lane >> 4) << 3)]);
                bfr[nf] = __builtin_bit_cast(bf16x8, r);
            }
            #pragma unroll
            for (int mf = 0; mf < 4; ++mf)
                #pragma unroll
                for (int nf = 0; nf < 4; ++nf)
                    acc[mf][nf] = __builtin_amdgcn_mfma_f32_16x16x32_bf16(af[mf], bfr[nf], acc[mf][nf], 0, 0, 0);
        }
        __syncthreads();
    }

    // ---- epilogue: scale per (e,col), f32 store, scatter by token id ----
    const int* toks = g_ids + base;
    float sc[4];
    #pragma unroll
    for (int nf = 0; nf < 4; ++nf)
        sc[nf] = scales[e * OUT_N + n0 + wn * 64 + nf * 16 + (lane & 15)];
    #pragma unroll
    for (int mf = 0; mf < 4; ++mf) {
        #pragma unroll
        for (int r = 0; r < 4; ++r) {
            const int row = m0 + wm * 64 + mf * 16 + ((lane >> 4) << 2) + r;
            if (row >= cnt) continue;
            int tok = toks[row];
            if ((unsigned)tok >= (unsigned)T_N) continue;
            float* yrow = y + (long)tok * OUT_N;
            #pragma unroll
            for (int nf = 0; nf < 4; ++nf) {
                const int col = n0 + wn * 64 + nf * 16 + (lane & 15);
                yrow[col] = acc[mf][nf][r] * sc[nf];
            }
        }
    }
}

extern "C" void kernel_launch(void* const* d_in, const int* in_sizes, int n_in,
                              void* d_out, int out_size, void* d_ws, size_t ws_size,
                              hipStream_t stream) {
    // Route inputs by element-count signature (order-robust):
    //   x: 33554432, indices: 8192, scales: 32768, qweight & meta: 8388608 each (dict order: qw first)
    const float* x      = nullptr;
    const int* indices  = nullptr;
    const int* qw       = nullptr;
    const void* meta    = nullptr;
    const float* scales = nullptr;
    int big_seen = 0;
    for (int i = 0; i < n_in; ++i) {
        long s = in_sizes[i];
        if (s == 33554432L)      x = (const float*)d_in[i];
        else if (s == 8192L)     indices = (const int*)d_in[i];
        else if (s == 32768L)    scales = (const float*)d_in[i];
        else if (s == 8388608L) {
            if (big_seen++ == 0)  qw = (const int*)d_in[i];
            else                  meta = d_in[i];
        }
    }
    if (!x || !indices || !qw || !meta || !scales) return;
    float* y = (float*)d_out;

    hipLaunchKernelGGL(sort_tokens, dim3(1), dim3(1024), 0, stream, indices, (const u16*)meta);
    hipLaunchKernelGGL(xb_convert, dim3(T_N), dim3(256), 0, stream, x);
    hipLaunchKernelGGL(decode_w, dim3(OUT_N / BN, IN_N / BK, E_N), dim3(NTHREADS), 0, stream, qw, meta);
    hipLaunchKernelGGL(moe_gemm, dim3(OUT_N / BN, T_N / BM, E_N), dim3(NTHREADS), 0, stream, scales, y);
}